// Round 1
// baseline (156.848 us; speedup 1.0000x reference)
//
#include <hip/hip_runtime.h>
#include <math.h>

#define B_ 2
#define N_ 5
#define C_ 256
#define H_ 64
#define W_ 64
#define PARA_ 256
#define H0_ 60
#define W0_ 60

// ---------------- Kernel 1: h = relu(pc @ W1^T + b1) ----------------
__global__ void k_mlp1(const float* __restrict__ pc, const float* __restrict__ W1,
                       const float* __restrict__ b1, float* __restrict__ h) {
    int b = blockIdx.x;
    int j = threadIdx.x;
    __shared__ float spc[PARA_];
    spc[j] = pc[b * PARA_ + j];
    __syncthreads();
    const float* wrow = W1 + (size_t)j * PARA_;
    float acc = b1[j];
    #pragma unroll 8
    for (int k = 0; k < PARA_; ++k) acc += spc[k] * wrow[k];
    h[b * PARA_ + j] = fmaxf(acc, 0.f);
}

// ---------------- Kernel 2: kpts/rad/sim heads ----------------
// per b: 2NC=2560 kpts dots, NC=1280 rad dots, 4NC=5120 sim dots => 8960 = 35 blocks of 256
__global__ void k_heads(const float* __restrict__ h,
                        const float* __restrict__ Wk, const float* __restrict__ bk,
                        const float* __restrict__ Ws, const float* __restrict__ bs,
                        const float* __restrict__ Wr, const float* __restrict__ br,
                        float* __restrict__ kpts, float* __restrict__ rad,
                        float* __restrict__ sim) {
    int b = blockIdx.x / 35;
    int m = (blockIdx.x % 35) * 256 + threadIdx.x;
    __shared__ float sh[PARA_];
    sh[threadIdx.x] = h[b * PARA_ + threadIdx.x];
    __syncthreads();

    const float* wrow;
    float bias;
    int kind, j;
    if (m < 2 * N_ * C_) {          // kpts
        j = m; wrow = Wk + (size_t)j * PARA_; bias = bk[j]; kind = 0;
    } else if (m < 3 * N_ * C_) {   // rad
        j = m - 2 * N_ * C_; wrow = Wr + (size_t)j * PARA_; bias = br[j]; kind = 1;
    } else {                        // sim
        j = m - 3 * N_ * C_; wrow = Ws + (size_t)j * PARA_; bias = bs[j]; kind = 2;
    }
    float acc = bias;
    #pragma unroll 8
    for (int k = 0; k < PARA_; ++k) acc += sh[k] * wrow[k];

    if (kind == 0)      kpts[b * 2 * N_ * C_ + j] = tanhf(acc);
    else if (kind == 1) rad [b * N_ * C_     + j] = 1.f / (1.f + expf(-acc));
    else                sim [b * 4 * N_ * C_ + j] = tanhf(acc);
}

// ---------------- Kernel 3: warp field -> scrambled layout ----------------
// graw[b,c,h0,w0,t]  with rfull = w0*120 + h0*2 + t:
//   c2 = 2c + (rfull>=3600); r = rfull mod 3600; hh = r/60; ww = r%60
//   scram[b, c2, hh, ww] = graw value
__global__ void k_warp(const float* __restrict__ kpts, const float* __restrict__ rad,
                       const float* __restrict__ sim, const float* __restrict__ grid0,
                       float* __restrict__ scram) {
    int idx = blockIdx.x * 256 + threadIdx.x;
    int w0 = idx % W0_;
    int tmp = idx / W0_;
    int h0 = tmp % H0_; tmp /= H0_;
    int c  = tmp % C_;
    int b  = tmp / C_;

    float gx = grid0[(h0 * W0_ + w0) * 2 + 0];
    float gy = grid0[(h0 * W0_ + w0) * 2 + 1];

    float numx = 0.f, numy = 0.f, den = 0.f;
    #pragma unroll
    for (int n = 0; n < N_; ++n) {
        int base = (b * N_ + n) * C_ + c;
        float kx = kpts[base * 2 + 0];
        float ky = kpts[base * 2 + 1];
        float rd = rad[base];
        float s0 = sim[base * 4 + 0];
        float s1 = sim[base * 4 + 1];
        float s2 = sim[base * 4 + 2];
        float s3 = sim[base * 4 + 3];

        float ox = gx - kx, oy = gy - ky;
        float dist = sqrtf(ox * ox + oy * oy);
        float e = expf(-dist / rd);
        float scale = (s0 + 1.f) * e + (1.f - e);
        float ang = s1 * 3.14159265358979323846f * e;
        float cth = cosf(ang), sth = sinf(ang);
        float rx =  ox * cth + oy * sth;
        float ry = -ox * sth + oy * cth;
        float wxv = scale * rx + s2 * e + kx;
        float wyv = scale * ry + s3 * e + ky;
        float sw = expf(e);   // softmax over N of e
        numx += wxv * sw;
        numy += wyv * sw;
        den  += sw;
    }
    float invden = 1.f / den;
    float g0 = numx * invden;
    float g1 = numy * invden;

    int rbase = w0 * 120 + h0 * 2;
    #pragma unroll
    for (int t = 0; t < 2; ++t) {
        int rfull = rbase + t;
        int hi = (rfull >= 3600) ? 1 : 0;
        int r = rfull - hi * 3600;
        int c2 = 2 * c + hi;
        int hh = r / 60;
        int ww = r - hh * 60;
        scram[(((size_t)b * 2 * C_ + c2) * H0_ + hh) * W0_ + ww] = (t == 0) ? g0 : g1;
    }
}

// ---------------- Kernel 4: bilinear 60->64 resize + 2D grid sample ----------------
// depth coordinate is exactly z_src = c, so the 3D trilinear sample collapses to
// bilinear on feature_map[b,c] with zeros padding (align_corners=False).
__global__ void k_sample(const float* __restrict__ scram, const float* __restrict__ fmap,
                         float* __restrict__ out) {
    int idx = blockIdx.x * 256 + threadIdx.x;
    int w = idx % W_;
    int tmp = idx / W_;
    int h = tmp % H_; tmp /= H_;
    int c = tmp % C_;
    int b = tmp / C_;

    // jax bilinear resize, half-pixel centers; edge renormalization == clamped taps
    const float sc = 60.f / 64.f;
    float chf = ((float)h + 0.5f) * sc - 0.5f;
    float cwf = ((float)w + 0.5f) * sc - 0.5f;
    int ih = (int)floorf(chf), iw = (int)floorf(cwf);
    float th = chf - (float)ih, tw = cwf - (float)iw;
    int ih0 = min(max(ih, 0), H0_ - 1), ih1 = min(max(ih + 1, 0), H0_ - 1);
    int iw0 = min(max(iw, 0), W0_ - 1), iw1 = min(max(iw + 1, 0), W0_ - 1);
    float w00 = (1.f - th) * (1.f - tw), w01 = (1.f - th) * tw;
    float w10 = th * (1.f - tw),         w11 = th * tw;

    float g[2];
    #pragma unroll
    for (int t = 0; t < 2; ++t) {
        const float* chp = scram + ((size_t)(b * 2 * C_ + 2 * c + t)) * (H0_ * W0_);
        g[t] = w00 * chp[ih0 * W0_ + iw0] + w01 * chp[ih0 * W0_ + iw1]
             + w10 * chp[ih1 * W0_ + iw0] + w11 * chp[ih1 * W0_ + iw1];
    }

    // grid_sample bilinear, zeros padding, align_corners=False on slice c
    float x = (g[0] + 1.f) * ((float)W_ * 0.5f) - 0.5f;
    float y = (g[1] + 1.f) * ((float)H_ * 0.5f) - 0.5f;
    int x0 = (int)floorf(x), y0 = (int)floorf(y);
    float tx = x - (float)x0, ty = y - (float)y0;
    const float* fm = fmap + ((size_t)(b * C_ + c)) * (H_ * W_);
    float acc = 0.f;
    #pragma unroll
    for (int dy = 0; dy < 2; ++dy) {
        int yi = y0 + dy;
        float wy = dy ? ty : (1.f - ty);
        if (yi < 0 || yi >= H_) continue;
        #pragma unroll
        for (int dx = 0; dx < 2; ++dx) {
            int xi = x0 + dx;
            float wx = dx ? tx : (1.f - tx);
            if (xi < 0 || xi >= W_) continue;
            acc += fm[yi * W_ + xi] * wy * wx;
        }
    }
    out[idx] = acc;
}

extern "C" void kernel_launch(void* const* d_in, const int* in_sizes, int n_in,
                              void* d_out, int out_size, void* d_ws, size_t ws_size,
                              hipStream_t stream) {
    const float* fmap  = (const float*)d_in[0];
    const float* pc    = (const float*)d_in[1];
    const float* W1    = (const float*)d_in[2];
    const float* b1    = (const float*)d_in[3];
    const float* Wk    = (const float*)d_in[4];
    const float* bk    = (const float*)d_in[5];
    const float* Ws    = (const float*)d_in[6];
    const float* bs    = (const float*)d_in[7];
    const float* Wr    = (const float*)d_in[8];
    const float* br    = (const float*)d_in[9];
    const float* grid0 = (const float*)d_in[10];

    float* ws = (float*)d_ws;
    float* h     = ws;                 // 512
    float* kpts  = ws + 512;           // 5120
    float* rad   = ws + 5632;          // 2560
    float* sim   = ws + 8192;          // 10240
    float* scram = ws + 18432;         // 2*512*3600 = 3,686,400

    k_mlp1 <<<B_, 256, 0, stream>>>(pc, W1, b1, h);
    k_heads<<<B_ * 35, 256, 0, stream>>>(h, Wk, bk, Ws, bs, Wr, br, kpts, rad, sim);
    k_warp <<<(B_ * C_ * H0_ * W0_) / 256, 256, 0, stream>>>(kpts, rad, sim, grid0, scram);
    k_sample<<<(B_ * C_ * H_ * W_) / 256, 256, 0, stream>>>(scram, fmap, (float*)d_out);
}

// Round 2
// 130.601 us; speedup vs baseline: 1.2010x; 1.2010x over previous
//
#include <hip/hip_runtime.h>
#include <math.h>

#define B_ 2
#define N_ 5
#define C_ 256
#define H_ 64
#define W_ 64
#define PARA_ 256
#define H0_ 60
#define W0_ 60
#define LOG2E 1.4426950408889634f

// ---------------- Kernel 1: h = relu(pc @ W1^T + b1) ----------------
__global__ void k_mlp1(const float* __restrict__ pc, const float* __restrict__ W1,
                       const float* __restrict__ b1, float* __restrict__ h) {
    int b = blockIdx.x;
    int j = threadIdx.x;
    __shared__ float spc[PARA_];
    spc[j] = pc[b * PARA_ + j];
    __syncthreads();
    const float* wrow = W1 + (size_t)j * PARA_;
    float acc = b1[j];
    #pragma unroll 8
    for (int k = 0; k < PARA_; ++k) acc += spc[k] * wrow[k];
    h[b * PARA_ + j] = fmaxf(acc, 0.f);
}

// ---------------- Kernel 2: kpts/rad/sim heads ----------------
__global__ void k_heads(const float* __restrict__ h,
                        const float* __restrict__ Wk, const float* __restrict__ bk,
                        const float* __restrict__ Ws, const float* __restrict__ bs,
                        const float* __restrict__ Wr, const float* __restrict__ br,
                        float* __restrict__ kpts, float* __restrict__ rad,
                        float* __restrict__ sim) {
    int b = blockIdx.x / 35;
    int m = (blockIdx.x % 35) * 256 + threadIdx.x;
    __shared__ float sh[PARA_];
    sh[threadIdx.x] = h[b * PARA_ + threadIdx.x];
    __syncthreads();

    const float* wrow;
    float bias;
    int kind, j;
    if (m < 2 * N_ * C_) {          // kpts
        j = m; wrow = Wk + (size_t)j * PARA_; bias = bk[j]; kind = 0;
    } else if (m < 3 * N_ * C_) {   // rad
        j = m - 2 * N_ * C_; wrow = Wr + (size_t)j * PARA_; bias = br[j]; kind = 1;
    } else {                        // sim
        j = m - 3 * N_ * C_; wrow = Ws + (size_t)j * PARA_; bias = bs[j]; kind = 2;
    }
    float acc = bias;
    #pragma unroll 8
    for (int k = 0; k < PARA_; ++k) acc += sh[k] * wrow[k];

    if (kind == 0)      kpts[b * 2 * N_ * C_ + j] = tanhf(acc);
    else if (kind == 1) rad [b * N_ * C_     + j] = 1.f / (1.f + expf(-acc));
    else                sim [b * 4 * N_ * C_ + j] = tanhf(acc);
}

// ---------------- Kernel 3: warp field -> scrambled layout ----------------
// flat scramble offset within the (b, 2c..2c+1) plane pair is exactly
//   rfull = w0*120 + h0*2 + t   (t = x/y component)
// and both t land in the same hi-half since rfull base is even.
// One block per (b, c, half); keypoint params are wave-uniform scalar loads.
__global__ __launch_bounds__(256) void k_warp(const float* __restrict__ kpts,
                       const float* __restrict__ rad,
                       const float* __restrict__ sim,
                       const float* __restrict__ grid0,
                       float* __restrict__ scram) {
    int blk  = blockIdx.x;
    int half = blk & 1;
    int bc   = blk >> 1;
    int c = bc % C_;
    int b = bc / C_;

    float kx[N_], ky[N_], nlr[N_], s0_[N_], s1h[N_], s2_[N_], s3_[N_];
    #pragma unroll
    for (int n = 0; n < N_; ++n) {
        int base = (b * N_ + n) * C_ + c;
        kx[n]  = kpts[base * 2 + 0];
        ky[n]  = kpts[base * 2 + 1];
        nlr[n] = -LOG2E * __builtin_amdgcn_rcpf(rad[base]);
        s0_[n] = sim[base * 4 + 0];
        s1h[n] = sim[base * 4 + 1] * 0.5f;   // ang/(2pi) = s1*e/2
        s2_[n] = sim[base * 4 + 2];
        s3_[n] = sim[base * 4 + 3];
    }

    float* plane = scram + ((size_t)(b * 2 * C_ + 2 * c)) * 3600;

    int qend = half * 1800 + 1800;
    for (int q = half * 1800 + threadIdx.x; q < qend; q += 256) {
        int h0 = q % 60, w0 = q / 60;   // h0-fastest => coalesced float2 store
        float2 g = *(const float2*)(grid0 + (h0 * W0_ + w0) * 2);
        float gx = g.x, gy = g.y;

        float numx = 0.f, numy = 0.f, den = 0.f;
        #pragma unroll
        for (int n = 0; n < N_; ++n) {
            float ox = gx - kx[n], oy = gy - ky[n];
            float dist = __builtin_amdgcn_sqrtf(fmaf(ox, ox, oy * oy));
            float e = __builtin_amdgcn_exp2f(dist * nlr[n]);
            float scale = fmaf(s0_[n], e, 1.f);
            float ar = s1h[n] * e;                       // revolutions
            float sn = __builtin_amdgcn_sinf(ar);
            float cs = __builtin_amdgcn_cosf(ar);
            float rx = fmaf(ox, cs, oy * sn);
            float ry = fmaf(oy, cs, -(ox * sn));
            float wxv = fmaf(scale, rx, fmaf(s2_[n], e, kx[n]));
            float wyv = fmaf(scale, ry, fmaf(s3_[n], e, ky[n]));
            float sw = __builtin_amdgcn_exp2f(e * LOG2E);
            numx = fmaf(wxv, sw, numx);
            numy = fmaf(wyv, sw, numy);
            den += sw;
        }
        float inv = __builtin_amdgcn_rcpf(den);
        float2 outv = make_float2(numx * inv, numy * inv);
        *(float2*)(plane + w0 * 120 + h0 * 2) = outv;
    }
}

// ---------------- Kernel 4: bilinear 60->64 resize + 2D grid sample ----------------
__global__ __launch_bounds__(256) void k_sample(const float* __restrict__ scram,
                         const float* __restrict__ fmap,
                         float* __restrict__ out) {
    int idx = blockIdx.x * 256 + threadIdx.x;
    int w = idx % W_;
    int tmp = idx / W_;
    int h = tmp % H_; tmp /= H_;
    int c = tmp % C_;
    int b = tmp / C_;

    // jax bilinear resize, half-pixel centers; edge renormalization == clamped taps
    const float sc = 60.f / 64.f;
    float chf = ((float)h + 0.5f) * sc - 0.5f;
    float cwf = ((float)w + 0.5f) * sc - 0.5f;
    int ih = (int)floorf(chf), iw = (int)floorf(cwf);
    float th = chf - (float)ih, tw = cwf - (float)iw;
    int ih0 = min(max(ih, 0), H0_ - 1), ih1 = min(max(ih + 1, 0), H0_ - 1);
    int iw0 = min(max(iw, 0), W0_ - 1), iw1 = min(max(iw + 1, 0), W0_ - 1);
    float w00 = (1.f - th) * (1.f - tw), w01 = (1.f - th) * tw;
    float w10 = th * (1.f - tw),         w11 = th * tw;

    float g[2];
    #pragma unroll
    for (int t = 0; t < 2; ++t) {
        const float* chp = scram + ((size_t)(b * 2 * C_ + 2 * c + t)) * (H0_ * W0_);
        g[t] = w00 * chp[ih0 * W0_ + iw0] + w01 * chp[ih0 * W0_ + iw1]
             + w10 * chp[ih1 * W0_ + iw0] + w11 * chp[ih1 * W0_ + iw1];
    }

    // grid_sample bilinear, zeros padding, align_corners=False on slice c
    float x = (g[0] + 1.f) * ((float)W_ * 0.5f) - 0.5f;
    float y = (g[1] + 1.f) * ((float)H_ * 0.5f) - 0.5f;
    int x0 = (int)floorf(x), y0 = (int)floorf(y);
    float tx = x - (float)x0, ty = y - (float)y0;
    const float* fm = fmap + ((size_t)(b * C_ + c)) * (H_ * W_);
    float acc = 0.f;
    #pragma unroll
    for (int dy = 0; dy < 2; ++dy) {
        int yi = y0 + dy;
        float wy = dy ? ty : (1.f - ty);
        if (yi < 0 || yi >= H_) continue;
        #pragma unroll
        for (int dx = 0; dx < 2; ++dx) {
            int xi = x0 + dx;
            float wx = dx ? tx : (1.f - tx);
            if (xi < 0 || xi >= W_) continue;
            acc += fm[yi * W_ + xi] * wy * wx;
        }
    }
    out[idx] = acc;
}

extern "C" void kernel_launch(void* const* d_in, const int* in_sizes, int n_in,
                              void* d_out, int out_size, void* d_ws, size_t ws_size,
                              hipStream_t stream) {
    const float* fmap  = (const float*)d_in[0];
    const float* pc    = (const float*)d_in[1];
    const float* W1    = (const float*)d_in[2];
    const float* b1    = (const float*)d_in[3];
    const float* Wk    = (const float*)d_in[4];
    const float* bk    = (const float*)d_in[5];
    const float* Ws    = (const float*)d_in[6];
    const float* bs    = (const float*)d_in[7];
    const float* Wr    = (const float*)d_in[8];
    const float* br    = (const float*)d_in[9];
    const float* grid0 = (const float*)d_in[10];

    float* ws = (float*)d_ws;
    float* h     = ws;                 // 512
    float* kpts  = ws + 512;           // 5120
    float* rad   = ws + 5632;          // 2560
    float* sim   = ws + 8192;          // 10240
    float* scram = ws + 18432;         // 2*512*3600 = 3,686,400

    k_mlp1 <<<B_, 256, 0, stream>>>(pc, W1, b1, h);
    k_heads<<<B_ * 35, 256, 0, stream>>>(h, Wk, bk, Ws, bs, Wr, br, kpts, rad, sim);
    k_warp <<<B_ * C_ * 2, 256, 0, stream>>>(kpts, rad, sim, grid0, scram);
    k_sample<<<(B_ * C_ * H_ * W_) / 256, 256, 0, stream>>>(scram, fmap, (float*)d_out);
}

// Round 3
// 116.330 us; speedup vs baseline: 1.3483x; 1.1227x over previous
//
#include <hip/hip_runtime.h>
#include <math.h>

#define B_ 2
#define N_ 5
#define C_ 256
#define H_ 64
#define W_ 64
#define PARA_ 256
#define H0_ 60
#define W0_ 60
#define LOG2E 1.4426950408889634f

// ---------------- Kernel 1: fused MLP + heads ----------------
// 70 blocks per batch-row chunk: block computes h[b] redundantly (W1 is L2-resident),
// then 256 head dots. Saves a kernel launch + global h round-trip.
__global__ __launch_bounds__(256) void k_heads(
        const float* __restrict__ pc, const float* __restrict__ W1,
        const float* __restrict__ b1,
        const float* __restrict__ Wk, const float* __restrict__ bk,
        const float* __restrict__ Ws, const float* __restrict__ bs,
        const float* __restrict__ Wr, const float* __restrict__ br,
        float* __restrict__ kpts, float* __restrict__ rad,
        float* __restrict__ sim) {
    int b = blockIdx.x / 35;
    int m = (blockIdx.x % 35) * 256 + threadIdx.x;
    int tid = threadIdx.x;

    __shared__ float spc[PARA_];
    __shared__ float sh[PARA_];
    spc[tid] = pc[b * PARA_ + tid];
    __syncthreads();

    // h[tid] = relu(pc . W1[tid,:] + b1[tid])
    {
        const float4* wrow = (const float4*)(W1 + (size_t)tid * PARA_);
        const float4* sp4 = (const float4*)spc;
        float acc = b1[tid];
        #pragma unroll 8
        for (int k = 0; k < PARA_ / 4; ++k) {
            float4 wv = wrow[k];
            float4 pv = sp4[k];
            acc += wv.x * pv.x + wv.y * pv.y + wv.z * pv.z + wv.w * pv.w;
        }
        sh[tid] = fmaxf(acc, 0.f);
    }
    __syncthreads();

    const float* wrow;
    float bias;
    int kind, j;
    if (m < 2 * N_ * C_) {          // kpts
        j = m; wrow = Wk + (size_t)j * PARA_; bias = bk[j]; kind = 0;
    } else if (m < 3 * N_ * C_) {   // rad
        j = m - 2 * N_ * C_; wrow = Wr + (size_t)j * PARA_; bias = br[j]; kind = 1;
    } else {                        // sim
        j = m - 3 * N_ * C_; wrow = Ws + (size_t)j * PARA_; bias = bs[j]; kind = 2;
    }
    const float4* w4 = (const float4*)wrow;
    const float4* h4 = (const float4*)sh;
    float acc = bias;
    #pragma unroll 8
    for (int k = 0; k < PARA_ / 4; ++k) {
        float4 wv = w4[k];
        float4 hv = h4[k];
        acc += wv.x * hv.x + wv.y * hv.y + wv.z * hv.z + wv.w * hv.w;
    }

    if (kind == 0)      kpts[b * 2 * N_ * C_ + j] = tanhf(acc);
    else if (kind == 1) rad [b * N_ * C_     + j] = 1.f / (1.f + expf(-acc));
    else                sim [b * 4 * N_ * C_ + j] = tanhf(acc);
}

// ---------------- Kernel 2: fused warp-field + resize + grid-sample ----------------
// One block per (b,c). Warp field for channel c is written to LDS at its
// scrambled flat offset rfull = w0*120 + h0*2 + t (28.8 KB); fmap[b,c] slice
// staged in LDS (16 KB). Sample phase reads only LDS.
__global__ __launch_bounds__(512) void k_fused(
        const float* __restrict__ kpts, const float* __restrict__ rad,
        const float* __restrict__ sim, const float* __restrict__ grid0,
        const float* __restrict__ fmap, float* __restrict__ out) {
    int c = blockIdx.x & (C_ - 1);
    int b = blockIdx.x >> 8;
    int tid = threadIdx.x;

    __shared__ __align__(16) float sg[7200];   // scrambled warp field, channel c
    __shared__ __align__(16) float sf[H_ * W_]; // fmap slice (b,c)

    // stage fmap plane (16 KB) as float4
    {
        const float4* fp = (const float4*)(fmap + ((size_t)(b * C_ + c)) * (H_ * W_));
        float4* sf4 = (float4*)sf;
        sf4[tid]       = fp[tid];
        sf4[tid + 512] = fp[tid + 512];
    }

    // block-uniform keypoint params
    float kx[N_], ky[N_], nlr[N_], s0_[N_], s1h[N_], s2_[N_], s3_[N_];
    #pragma unroll
    for (int n = 0; n < N_; ++n) {
        int base = (b * N_ + n) * C_ + c;
        kx[n]  = kpts[base * 2 + 0];
        ky[n]  = kpts[base * 2 + 1];
        nlr[n] = -LOG2E * __builtin_amdgcn_rcpf(rad[base]);
        s0_[n] = sim[base * 4 + 0];
        s1h[n] = sim[base * 4 + 1] * 0.5f;   // revolutions = s1*e/2
        s2_[n] = sim[base * 4 + 2];
        s3_[n] = sim[base * 4 + 3];
    }

    // warp phase: 3600 pixels, h0-fastest => LDS float2 write stride-2 (free)
    for (int q = tid; q < H0_ * W0_; q += 512) {
        int h0 = q % 60, w0 = q / 60;
        float2 g = *(const float2*)(grid0 + (h0 * W0_ + w0) * 2);
        float gx = g.x, gy = g.y;

        float numx = 0.f, numy = 0.f, den = 0.f;
        #pragma unroll
        for (int n = 0; n < N_; ++n) {
            float ox = gx - kx[n], oy = gy - ky[n];
            float dist = __builtin_amdgcn_sqrtf(fmaf(ox, ox, oy * oy));
            float e = __builtin_amdgcn_exp2f(dist * nlr[n]);
            float scale = fmaf(s0_[n], e, 1.f);
            float ar = s1h[n] * e;
            float sn = __builtin_amdgcn_sinf(ar);
            float cs = __builtin_amdgcn_cosf(ar);
            float rx = fmaf(ox, cs, oy * sn);
            float ry = fmaf(oy, cs, -(ox * sn));
            float wxv = fmaf(scale, rx, fmaf(s2_[n], e, kx[n]));
            float wyv = fmaf(scale, ry, fmaf(s3_[n], e, ky[n]));
            float sw = __builtin_amdgcn_exp2f(e * LOG2E);
            numx = fmaf(wxv, sw, numx);
            numy = fmaf(wyv, sw, numy);
            den += sw;
        }
        float inv = __builtin_amdgcn_rcpf(den);
        *(float2*)(sg + w0 * 120 + h0 * 2) = make_float2(numx * inv, numy * inv);
    }
    __syncthreads();

    // sample phase: 4096 output pixels from LDS only
    float* outp = out + ((size_t)(b * C_ + c)) * (H_ * W_);
    for (int p = tid; p < H_ * W_; p += 512) {
        int w = p & (W_ - 1);
        int h = p >> 6;

        const float sc = 60.f / 64.f;
        float chf = ((float)h + 0.5f) * sc - 0.5f;
        float cwf = ((float)w + 0.5f) * sc - 0.5f;
        int ih = (int)floorf(chf), iw = (int)floorf(cwf);
        float th = chf - (float)ih, tw = cwf - (float)iw;
        int ih0 = min(max(ih, 0), H0_ - 1), ih1 = min(max(ih + 1, 0), H0_ - 1);
        int iw0 = min(max(iw, 0), W0_ - 1), iw1 = min(max(iw + 1, 0), W0_ - 1);
        float w00 = (1.f - th) * (1.f - tw), w01 = (1.f - th) * tw;
        float w10 = th * (1.f - tw),         w11 = th * tw;

        float g0 = w00 * sg[ih0 * 60 + iw0] + w01 * sg[ih0 * 60 + iw1]
                 + w10 * sg[ih1 * 60 + iw0] + w11 * sg[ih1 * 60 + iw1];
        float g1 = w00 * sg[3600 + ih0 * 60 + iw0] + w01 * sg[3600 + ih0 * 60 + iw1]
                 + w10 * sg[3600 + ih1 * 60 + iw0] + w11 * sg[3600 + ih1 * 60 + iw1];

        // grid_sample bilinear, zeros padding, align_corners=False
        float x = (g0 + 1.f) * ((float)W_ * 0.5f) - 0.5f;
        float y = (g1 + 1.f) * ((float)H_ * 0.5f) - 0.5f;
        int x0 = (int)floorf(x), y0 = (int)floorf(y);
        float tx = x - (float)x0, ty = y - (float)y0;
        float acc = 0.f;
        #pragma unroll
        for (int dy = 0; dy < 2; ++dy) {
            int yi = y0 + dy;
            float wy = dy ? ty : (1.f - ty);
            if (yi < 0 || yi >= H_) continue;
            #pragma unroll
            for (int dx = 0; dx < 2; ++dx) {
                int xi = x0 + dx;
                float wx = dx ? tx : (1.f - tx);
                if (xi < 0 || xi >= W_) continue;
                acc += sf[yi * W_ + xi] * wy * wx;
            }
        }
        outp[p] = acc;
    }
}

extern "C" void kernel_launch(void* const* d_in, const int* in_sizes, int n_in,
                              void* d_out, int out_size, void* d_ws, size_t ws_size,
                              hipStream_t stream) {
    const float* fmap  = (const float*)d_in[0];
    const float* pc    = (const float*)d_in[1];
    const float* W1    = (const float*)d_in[2];
    const float* b1    = (const float*)d_in[3];
    const float* Wk    = (const float*)d_in[4];
    const float* bk    = (const float*)d_in[5];
    const float* Ws    = (const float*)d_in[6];
    const float* bs    = (const float*)d_in[7];
    const float* Wr    = (const float*)d_in[8];
    const float* br    = (const float*)d_in[9];
    const float* grid0 = (const float*)d_in[10];

    float* ws = (float*)d_ws;
    float* kpts = ws;           // 5120
    float* rad  = ws + 5120;    // 2560
    float* sim  = ws + 7680;    // 10240

    k_heads<<<B_ * 35, 256, 0, stream>>>(pc, W1, b1, Wk, bk, Ws, bs, Wr, br,
                                         kpts, rad, sim);
    k_fused<<<B_ * C_, 512, 0, stream>>>(kpts, rad, sim, grid0, fmap, (float*)d_out);
}